// Round 1
// baseline (88.967 us; speedup 1.0000x reference)
//
#include <hip/hip_runtime.h>

#define TPB 256
#define PER_THREAD 32
#define CHUNK (TPB * PER_THREAD)   // 8192 elements per block
#define MAX_SCAN_BLOCKS 4096

// ---------------------------------------------------------------------------
// Exclusive block-wide scan of one unsigned per thread. wtot is LDS[TPB/64].
// ---------------------------------------------------------------------------
__device__ __forceinline__ unsigned block_excl_scan(unsigned tsum, unsigned* wtot) {
    const int lane = threadIdx.x & 63;
    const int wid  = threadIdx.x >> 6;
    unsigned v = tsum;
#pragma unroll
    for (int off = 1; off < 64; off <<= 1) {
        unsigned u = __shfl_up(v, off, 64);
        if (lane >= off) v += u;
    }
    if (lane == 63) wtot[wid] = v;
    __syncthreads();
    unsigned woff = 0;
    for (int w = 0; w < wid; ++w) woff += wtot[w];
    return woff + v - tsum;   // exclusive prefix for this thread
}

// ---------------------------------------------------------------------------
// Pass 1: per-block positive counts of `score` over contiguous CHUNK chunks.
// ---------------------------------------------------------------------------
__global__ void k_count(const float* __restrict__ score,
                        unsigned* __restrict__ blockCount, long n) {
    const long base = (long)blockIdx.x * CHUNK;
    const int tid = threadIdx.x;
    unsigned cnt = 0;
    if (base + CHUNK <= n) {
        const float4* s4 = reinterpret_cast<const float4*>(score + base);
#pragma unroll 4
        for (int q = tid; q < CHUNK / 4; q += TPB) {
            float4 v = s4[q];
            cnt += (unsigned)(v.x > 0.f) + (unsigned)(v.y > 0.f)
                 + (unsigned)(v.z > 0.f) + (unsigned)(v.w > 0.f);
        }
    } else {
        for (long i = base + tid; i < n; i += TPB) cnt += (unsigned)(score[i] > 0.f);
    }
#pragma unroll
    for (int off = 32; off > 0; off >>= 1) cnt += __shfl_down(cnt, off, 64);
    __shared__ unsigned wsum[TPB / 64];
    const int lane = tid & 63, wid = tid >> 6;
    if (lane == 0) wsum[wid] = cnt;
    __syncthreads();
    if (tid == 0) {
        unsigned tot = 0;
        for (int w = 0; w < TPB / 64; ++w) tot += wsum[w];
        blockCount[blockIdx.x] = tot;
    }
}

// ---------------------------------------------------------------------------
// Pass 1.5: single-block scan of block counts -> exclusive offsets + scalars.
// scalars[0]=S (=P as float), scalars[1]=sumS (float), scalars[2]=P (float)
// ---------------------------------------------------------------------------
__global__ void k_scan(const unsigned* __restrict__ blockCount,
                       unsigned* __restrict__ blockOffset,
                       float* __restrict__ scalars, int B) {
    __shared__ unsigned cnts[MAX_SCAN_BLOCKS];
    __shared__ unsigned wtot[TPB / 64];
    const int tid = threadIdx.x;
    for (int j = tid; j < B; j += TPB) cnts[j] = blockCount[j];
    __syncthreads();
    const int E = (B + TPB - 1) / TPB;
    const int start = tid * E;
    unsigned tsum = 0;
    for (int e = 0; e < E; ++e) {
        int j = start + e;
        if (j < B) tsum += cnts[j];
    }
    unsigned run = block_excl_scan(tsum, wtot);
    for (int e = 0; e < E; ++e) {
        int j = start + e;
        if (j < B) { unsigned c = cnts[j]; blockOffset[j] = run; run += c; }
    }
    if (tid == TPB - 1) {
        unsigned P = run;                      // total positives
        float S = (float)P;                    // sum(score): 0/1 values, exact
        float inv = 1.0f / S;                  // fl32(1/S) = s value at positives
        double sumS_d = (double)inv * (double)P;  // ~ pairwise sum of P copies
        scalars[0] = S;
        scalars[1] = (float)sumS_d;
        scalars[2] = (float)P;
    }
}

// ---------------------------------------------------------------------------
// Pass 2: the main elementwise+rank pass. Each thread owns PER_THREAD
// contiguous elements; exact integer running rank via block scan.
// ---------------------------------------------------------------------------
__global__ void k_main(const float* __restrict__ predict,
                       const float* __restrict__ score,
                       const unsigned* __restrict__ blockOffset,
                       const float* __restrict__ scalars,
                       double* __restrict__ blockSum, long n) {
    const int tid = threadIdx.x;
    const long base  = (long)blockIdx.x * CHUNK;
    const long tbase = base + (long)tid * PER_THREAD;
    const float S    = scalars[0];
    const float sumS = scalars[1];
    const float Pf   = scalars[2];

    __shared__ unsigned wtot[TPB / 64];
    __shared__ double   dsum[TPB / 64];

    const bool full = (tbase + PER_THREAD <= n);
    unsigned cnt = 0;
    float4 sc[PER_THREAD / 4];
    if (full) {
        const float4* s4 = reinterpret_cast<const float4*>(score + tbase);
#pragma unroll
        for (int q = 0; q < PER_THREAD / 4; ++q) {
            sc[q] = s4[q];
            cnt += (unsigned)(sc[q].x > 0.f) + (unsigned)(sc[q].y > 0.f)
                 + (unsigned)(sc[q].z > 0.f) + (unsigned)(sc[q].w > 0.f);
        }
    } else {
        // tail block: count only; phase B re-reads from global (keeps sc in regs)
        for (int e = 0; e < PER_THREAD; ++e) {
            long gi = tbase + e;
            if (gi < n) cnt += (unsigned)(score[gi] > 0.f);
        }
    }

    unsigned excl = block_excl_scan(cnt, wtot);
    unsigned run = blockOffset[blockIdx.x] + excl;  // positives strictly before 1st elem

    double acc = 0.0;
    if (full) {
        const float4* p4 = reinterpret_cast<const float4*>(predict + tbase);
#pragma unroll
        for (int q = 0; q < PER_THREAD / 4; ++q) {
            float4 pv4 = p4[q];
            float pv[4] = {pv4.x, pv4.y, pv4.z, pv4.w};
            float sv[4] = {sc[q].x, sc[q].y, sc[q].z, sc[q].w};
#pragma unroll
            for (int j = 0; j < 4; ++j) {
                long gi = tbase + q * 4 + j;
                float p = pv[j] / sumS;
                float t;
                if (sv[j] > 0.f) {
                    float kf = (float)(run + 1u);          // inclusive rank, exact
                    t = p / (kf + 1.0f) - (sv[j] / S) / __log2f(kf + 1.0f);
                    run += 1u;
                } else {
                    float mf = (float)(unsigned)(gi + 1 - (long)run);  // inclusive neg rank
                    t = p / ((Pf + mf) + 1.0f);
                }
                acc += (double)(t * t);
            }
        }
    } else {
        for (int e = 0; e < PER_THREAD; ++e) {
            long gi = tbase + e;
            if (gi >= n) break;
            float svv = score[gi];
            float p = predict[gi] / sumS;
            float t;
            if (svv > 0.f) {
                float kf = (float)(run + 1u);
                t = p / (kf + 1.0f) - (svv / S) / __log2f(kf + 1.0f);
                run += 1u;
            } else {
                float mf = (float)(unsigned)(gi + 1 - (long)run);
                t = p / ((Pf + mf) + 1.0f);
            }
            acc += (double)(t * t);
        }
    }

    // deterministic block reduce (tree within wave, then fixed-order across waves)
#pragma unroll
    for (int off = 32; off > 0; off >>= 1) acc += __shfl_down(acc, off, 64);
    const int lane = tid & 63, wid = tid >> 6;
    if (lane == 0) dsum[wid] = acc;
    __syncthreads();
    if (tid == 0) {
        double tot = 0.0;
        for (int w = 0; w < TPB / 64; ++w) tot += dsum[w];
        blockSum[blockIdx.x] = tot;
    }
}

// ---------------------------------------------------------------------------
// Pass 3: deterministic reduce of per-block doubles -> float scalar.
// ---------------------------------------------------------------------------
__global__ void k_final(const double* __restrict__ blockSum,
                        float* __restrict__ out, int B) {
    const int tid = threadIdx.x;
    double acc = 0.0;
    for (int j = tid; j < B; j += TPB) acc += blockSum[j];
#pragma unroll
    for (int off = 32; off > 0; off >>= 1) acc += __shfl_down(acc, off, 64);
    __shared__ double dsum[TPB / 64];
    const int lane = tid & 63, wid = tid >> 6;
    if (lane == 0) dsum[wid] = acc;
    __syncthreads();
    if (tid == 0) {
        double tot = 0.0;
        for (int w = 0; w < TPB / 64; ++w) tot += dsum[w];
        out[0] = (float)tot;
    }
}

extern "C" void kernel_launch(void* const* d_in, const int* in_sizes, int n_in,
                              void* d_out, int out_size, void* d_ws, size_t ws_size,
                              hipStream_t stream) {
    const float* predict = (const float*)d_in[0];
    const float* score   = (const float*)d_in[1];
    const long n = (long)in_sizes[0];
    const int B = (int)((n + CHUNK - 1) / CHUNK);   // 2048 for N=2^24

    unsigned char* ws = (unsigned char*)d_ws;
    unsigned* blockCount  = (unsigned*)ws;
    unsigned* blockOffset = (unsigned*)(ws + (size_t)B * sizeof(unsigned));
    float*    scalars     = (float*)(ws + (size_t)B * 2 * sizeof(unsigned));
    size_t off = ((size_t)B * 2 * sizeof(unsigned) + 4 * sizeof(float) + 255) & ~(size_t)255;
    double*   blockSum    = (double*)(ws + off);

    k_count<<<B, TPB, 0, stream>>>(score, blockCount, n);
    k_scan<<<1, TPB, 0, stream>>>(blockCount, blockOffset, scalars, B);
    k_main<<<B, TPB, 0, stream>>>(predict, score, blockOffset, scalars, blockSum, n);
    k_final<<<1, TPB, 0, stream>>>(blockSum, (float*)d_out, B);
}

// Round 2
// 44.518 us; speedup vs baseline: 1.9984x; 1.9984x over previous
//
#include <hip/hip_runtime.h>

#define TPB 256
#define PER_THREAD 32
#define CHUNK (TPB * PER_THREAD)   // 8192 elements per block
#define MAX_SCAN_BLOCKS 4096

// ---------------------------------------------------------------------------
// Exclusive block-wide scan of one unsigned per thread. wtot is LDS[TPB/64].
// ---------------------------------------------------------------------------
__device__ __forceinline__ unsigned block_excl_scan(unsigned tsum, unsigned* wtot) {
    const int lane = threadIdx.x & 63;
    const int wid  = threadIdx.x >> 6;
    unsigned v = tsum;
#pragma unroll
    for (int off = 1; off < 64; off <<= 1) {
        unsigned u = __shfl_up(v, off, 64);
        if (lane >= off) v += u;
    }
    if (lane == 63) wtot[wid] = v;
    __syncthreads();
    unsigned woff = 0;
    for (int w = 0; w < wid; ++w) woff += wtot[w];
    return woff + v - tsum;   // exclusive prefix for this thread
}

// ---------------------------------------------------------------------------
// Pass 1: per-block positive counts + per-thread 32-bit positivity masks.
// Each thread owns PER_THREAD contiguous elements; bit e of its mask word
// corresponds to element (block*CHUNK + tid*PER_THREAD + e).
// ---------------------------------------------------------------------------
__global__ void k_count(const float* __restrict__ score,
                        unsigned* __restrict__ blockCount,
                        unsigned* __restrict__ mask, long n) {
    const long base  = (long)blockIdx.x * CHUNK;
    const int  tid   = threadIdx.x;
    const long tbase = base + (long)tid * PER_THREAD;
    unsigned m = 0;
    if (tbase + PER_THREAD <= n) {
        const float4* s4 = reinterpret_cast<const float4*>(score + tbase);
#pragma unroll
        for (int q = 0; q < PER_THREAD / 4; ++q) {
            float4 v = s4[q];
            m |= ((unsigned)(v.x > 0.f)) << (4 * q + 0);
            m |= ((unsigned)(v.y > 0.f)) << (4 * q + 1);
            m |= ((unsigned)(v.z > 0.f)) << (4 * q + 2);
            m |= ((unsigned)(v.w > 0.f)) << (4 * q + 3);
        }
    } else {
        for (int e = 0; e < PER_THREAD; ++e) {
            long gi = tbase + e;
            if (gi < n && score[gi] > 0.f) m |= (1u << e);
        }
    }
    if (mask) mask[(size_t)blockIdx.x * TPB + tid] = m;

    unsigned cnt = __popc(m);
#pragma unroll
    for (int off = 32; off > 0; off >>= 1) cnt += __shfl_down(cnt, off, 64);
    __shared__ unsigned wsum[TPB / 64];
    const int lane = tid & 63, wid = tid >> 6;
    if (lane == 0) wsum[wid] = cnt;
    __syncthreads();
    if (tid == 0) {
        unsigned tot = 0;
        for (int w = 0; w < TPB / 64; ++w) tot += wsum[w];
        blockCount[blockIdx.x] = tot;
    }
}

// ---------------------------------------------------------------------------
// Pass 1.5: single-block scan of block counts -> exclusive offsets + scalars.
// scalars: [0]=S  [1]=sumS  [2]=P(float)  [3]=invS=1/S  [4]=1/sumS
// ---------------------------------------------------------------------------
__global__ void k_scan(const unsigned* __restrict__ blockCount,
                       unsigned* __restrict__ blockOffset,
                       float* __restrict__ scalars, int B) {
    __shared__ unsigned cnts[MAX_SCAN_BLOCKS];
    __shared__ unsigned wtot[TPB / 64];
    const int tid = threadIdx.x;
    for (int j = tid; j < B; j += TPB) cnts[j] = blockCount[j];
    __syncthreads();
    const int E = (B + TPB - 1) / TPB;
    const int start = tid * E;
    unsigned tsum = 0;
    for (int e = 0; e < E; ++e) {
        int j = start + e;
        if (j < B) tsum += cnts[j];
    }
    unsigned run = block_excl_scan(tsum, wtot);
    for (int e = 0; e < E; ++e) {
        int j = start + e;
        if (j < B) { unsigned c = cnts[j]; blockOffset[j] = run; run += c; }
    }
    if (tid == TPB - 1) {
        unsigned P = run;                          // total positives
        float S = (float)P;                        // sum(score): 0/1, exact
        float inv = 1.0f / S;                      // s value at positives
        double sumS_d = (double)inv * (double)P;   // ~ pairwise sum of P copies
        float sumS = (float)sumS_d;
        scalars[0] = S;
        scalars[1] = sumS;
        scalars[2] = (float)P;
        scalars[3] = inv;
        scalars[4] = 1.0f / sumS;
    }
}

// ---------------------------------------------------------------------------
// Pass 2: main pass. USE_MASK=true: score never touched (bits from mask).
// USE_MASK=false fallback: recompute bits from score (ws too small for mask).
// All divides replaced by v_rcp_f32 multiplies (±1ulp; far within tolerance).
// ---------------------------------------------------------------------------
template <bool USE_MASK>
__global__ void k_main(const float* __restrict__ predict,
                       const float* __restrict__ score,
                       const unsigned* __restrict__ mask,
                       const unsigned* __restrict__ blockOffset,
                       const float* __restrict__ scalars,
                       double* __restrict__ blockSum, long n) {
    const int  tid   = threadIdx.x;
    const long base  = (long)blockIdx.x * CHUNK;
    const long tbase = base + (long)tid * PER_THREAD;

    const float sumS    = scalars[1];
    const float Pf      = scalars[2];
    const float invS    = scalars[3];
    const float rcpSumS = scalars[4];

    __shared__ unsigned wtot[TPB / 64];
    __shared__ double   dsum[TPB / 64];

    const bool full = (tbase + PER_THREAD <= n);

    // --- build / load this thread's 32-bit positivity mask ---
    unsigned m = 0;
    if (USE_MASK) {
        m = mask[(size_t)blockIdx.x * TPB + tid];
    } else {
        if (full) {
            const float4* s4 = reinterpret_cast<const float4*>(score + tbase);
#pragma unroll
            for (int q = 0; q < PER_THREAD / 4; ++q) {
                float4 v = s4[q];
                m |= ((unsigned)(v.x > 0.f)) << (4 * q + 0);
                m |= ((unsigned)(v.y > 0.f)) << (4 * q + 1);
                m |= ((unsigned)(v.z > 0.f)) << (4 * q + 2);
                m |= ((unsigned)(v.w > 0.f)) << (4 * q + 3);
            }
        } else {
            for (int e = 0; e < PER_THREAD; ++e) {
                long gi = tbase + e;
                if (gi < n && score[gi] > 0.f) m |= (1u << e);
            }
        }
    }

    unsigned cnt  = __popc(m);
    unsigned excl = block_excl_scan(cnt, wtot);
    unsigned run  = blockOffset[blockIdx.x] + excl;  // positives strictly before

    double acc = 0.0;
    if (full) {
        const float4* p4 = reinterpret_cast<const float4*>(predict + tbase);
#pragma unroll
        for (int q = 0; q < PER_THREAD / 4; ++q) {
            float4 pv4 = p4[q];
            float pv[4] = {pv4.x, pv4.y, pv4.z, pv4.w};
#pragma unroll
            for (int j = 0; j < 4; ++j) {
                const int e = 4 * q + j;
                const bool ispos = (m >> e) & 1u;
                const unsigned newrun = run + (ispos ? 1u : 0u);
                const float p = pv[j] * rcpSumS;
                // positive branch value: k = newrun (inclusive rank)
                const float kp1  = (float)(newrun + 1u);
                const float posv = p * __builtin_amdgcn_rcpf(kp1)
                                 - invS * __builtin_amdgcn_rcpf(__log2f(kp1));
                // negative branch value: m_incl = (gi+1) - newrun
                const unsigned mr = (unsigned)(tbase + e + 1) - newrun;
                const float negv  = p * __builtin_amdgcn_rcpf(Pf + (float)mr + 1.0f);
                const float t = ispos ? posv : negv;
                acc += (double)(t * t);
                run = newrun;
            }
        }
    } else {
        for (int e = 0; e < PER_THREAD; ++e) {
            long gi = tbase + e;
            if (gi >= n) break;
            const bool ispos = (m >> e) & 1u;
            const unsigned newrun = run + (ispos ? 1u : 0u);
            const float p = predict[gi] * rcpSumS;
            const float kp1  = (float)(newrun + 1u);
            const float posv = p * __builtin_amdgcn_rcpf(kp1)
                             - invS * __builtin_amdgcn_rcpf(__log2f(kp1));
            const unsigned mr = (unsigned)(gi + 1) - newrun;
            const float negv  = p * __builtin_amdgcn_rcpf(Pf + (float)mr + 1.0f);
            const float t = ispos ? posv : negv;
            acc += (double)(t * t);
            run = newrun;
        }
    }

    // deterministic block reduce
#pragma unroll
    for (int off = 32; off > 0; off >>= 1) acc += __shfl_down(acc, off, 64);
    const int lane = tid & 63, wid = tid >> 6;
    if (lane == 0) dsum[wid] = acc;
    __syncthreads();
    if (tid == 0) {
        double tot = 0.0;
        for (int w = 0; w < TPB / 64; ++w) tot += dsum[w];
        blockSum[blockIdx.x] = tot;
    }
}

// ---------------------------------------------------------------------------
// Pass 3: deterministic reduce of per-block doubles -> float scalar.
// ---------------------------------------------------------------------------
__global__ void k_final(const double* __restrict__ blockSum,
                        float* __restrict__ out, int B) {
    const int tid = threadIdx.x;
    double acc = 0.0;
    for (int j = tid; j < B; j += TPB) acc += blockSum[j];
#pragma unroll
    for (int off = 32; off > 0; off >>= 1) acc += __shfl_down(acc, off, 64);
    __shared__ double dsum[TPB / 64];
    const int lane = tid & 63, wid = tid >> 6;
    if (lane == 0) dsum[wid] = acc;
    __syncthreads();
    if (tid == 0) {
        double tot = 0.0;
        for (int w = 0; w < TPB / 64; ++w) tot += dsum[w];
        out[0] = (float)tot;
    }
}

extern "C" void kernel_launch(void* const* d_in, const int* in_sizes, int n_in,
                              void* d_out, int out_size, void* d_ws, size_t ws_size,
                              hipStream_t stream) {
    const float* predict = (const float*)d_in[0];
    const float* score   = (const float*)d_in[1];
    const long n = (long)in_sizes[0];
    const int B = (int)((n + CHUNK - 1) / CHUNK);   // 2048 for N=2^24

    unsigned char* ws = (unsigned char*)d_ws;
    size_t off = 0;
    unsigned* blockCount  = (unsigned*)(ws + off); off += (size_t)B * sizeof(unsigned);
    unsigned* blockOffset = (unsigned*)(ws + off); off += (size_t)B * sizeof(unsigned);
    float*    scalars     = (float*)(ws + off);    off += 8 * sizeof(float);
    off = (off + 255) & ~(size_t)255;
    double*   blockSum    = (double*)(ws + off);   off += (size_t)B * sizeof(double);
    off = (off + 255) & ~(size_t)255;
    unsigned* maskBuf     = (unsigned*)(ws + off);
    const size_t maskBytes = (size_t)B * TPB * sizeof(unsigned);
    const bool useMask = (off + maskBytes) <= ws_size;

    k_count<<<B, TPB, 0, stream>>>(score, blockCount, useMask ? maskBuf : nullptr, n);
    k_scan<<<1, TPB, 0, stream>>>(blockCount, blockOffset, scalars, B);
    if (useMask)
        k_main<true><<<B, TPB, 0, stream>>>(predict, nullptr, maskBuf, blockOffset,
                                            scalars, blockSum, n);
    else
        k_main<false><<<B, TPB, 0, stream>>>(predict, score, nullptr, blockOffset,
                                             scalars, blockSum, n);
    k_final<<<1, TPB, 0, stream>>>(blockSum, (float*)d_out, B);
}